// Round 1
// baseline (311.118 us; speedup 1.0000x reference)
//
#include <hip/hip_runtime.h>
#include <math.h>

// ---------------- problem constants ----------------
constexpr int N_    = 10000;
constexpr int E_    = 320000;
constexpr int IND   = 128;
constexpr int HID   = 32;
constexpr int OUTD  = 128;
constexpr int NIV   = 33;      // max intervals = 32 breakpoints + 1
constexpr float EPS = 1e-5f;

// ---------------- workspace layout (float/int element offsets, 4B each) ----
constexpr size_t OFF_SUMH = 0;                    // 128 f
constexpr size_t OFF_SQH  = 128;                  // 128 f
constexpr size_t OFF_SUMP = 256;                  // 32 f
constexpr size_t OFF_SQP  = 288;                  // 32 f
constexpr size_t OFF_SUMU = 320;                  // 32 f
constexpr size_t OFF_SQU  = 352;                  // 32 f
constexpr size_t OFF_SUMO = 384;                  // 128 f
constexpr size_t OFF_SQO  = 512;                  // 128 f
constexpr size_t OFF_OCC  = 640;                  // 33 i
constexpr size_t OFF_DEG  = 704;                  // 10000 i
constexpr size_t OFF_UPD  = 10752;                // N*HID f
constexpr size_t ZERO_CNT = OFF_UPD + (size_t)N_*HID;        // 330752 elements zeroed
constexpr size_t OFF_BPS  = ZERO_CNT;             // 32 f sorted breakpoints
constexpr size_t OFF_M    = OFF_BPS + 32;         // 1 i
constexpr size_t OFF_C1   = 330816;               // 33*1056 f
constexpr size_t OFF_C0   = OFF_C1 + (size_t)NIV*1056;       // 365664
constexpr size_t OFF_P    = OFF_C0 + (size_t)NIV*1056;       // 400512, N*HID
constexpr size_t OFF_Q    = OFF_P + (size_t)N_*HID;          // 720512, N*HID
constexpr size_t OFF_IDX  = OFF_Q + (size_t)N_*HID;          // 1040512, E ints
constexpr size_t OFF_Y    = OFF_IDX + (size_t)E_;            // 1360512, slots*N*64 f

// ---------------- K_bp: breakpoints + per-interval C tables -----------------
__global__ __launch_bounds__(128)
void k_intervals(const float* __restrict__ kw1, const float* __restrict__ kb1,
                 const float* __restrict__ kw2, const float* __restrict__ kb2,
                 float* __restrict__ ws) {
    __shared__ float sel1[32], sel0[32];
    int* wsi = (int*)ws;
    int i = blockIdx.x;                 // interval id 0..32
    if (threadIdx.x == 0) {
        float bp[32]; int m = 0;
        for (int t = 0; t < 32; ++t) {
            float w = kw1[t];
            if (w != 0.f) bp[m++] = -kb1[t] / w;
        }
        for (int a = 1; a < m; ++a) {   // insertion sort
            float v = bp[a]; int b = a - 1;
            while (b >= 0 && bp[b] > v) { bp[b+1] = bp[b]; --b; }
            bp[b+1] = v;
        }
        if (i == 0) {
            for (int k = 0; k < 32; ++k) ws[OFF_BPS + k] = (k < m) ? bp[k] : 0.f;
            wsi[OFF_M] = m;
        }
        // representative point for interval i = (bp[i-1], bp[i]]
        float arep;
        if (m == 0 || i > m) arep = 0.f;
        else if (i == 0)     arep = bp[0]   - (1.f + 0.5f*fabsf(bp[0]));
        else if (i == m)     arep = bp[m-1] + (1.f + 0.5f*fabsf(bp[m-1]));
        else                 arep = (bp[i-1] < bp[i]) ? 0.5f*(bp[i-1] + bp[i]) : bp[i-1];
        for (int t = 0; t < 32; ++t) {
            bool s = (arep * kw1[t] + kb1[t]) > 0.f;
            sel1[t] = s ? kw1[t] : 0.f;
            sel0[t] = s ? kb1[t] : 0.f;
        }
    }
    __syncthreads();
    for (int r = threadIdx.x; r < 1056; r += blockDim.x) {
        float a1 = 0.f, a0 = 0.f;
        for (int t = 0; t < 32; ++t) {
            float w = kw2[r*32 + t];
            a1 += w * sel1[t];
            a0 += w * sel0[t];
        }
        ws[OFF_C1 + (size_t)i*1056 + r] = a1;
        ws[OFF_C0 + (size_t)i*1056 + r] = a0 + kb2[r];
    }
}

// ---------------- K1: column stats of H -------------------------------------
__global__ __launch_bounds__(256)
void k_stats_H(const float* __restrict__ H, float* __restrict__ ws) {
    __shared__ float shS[256], shQ[256];
    int t = threadIdx.x;
    int col = t & 127, half = t >> 7;
    float s = 0.f, q = 0.f;
    for (int r = blockIdx.x*2 + half; r < N_; r += gridDim.x*2) {
        float x = H[(size_t)r*IND + col];
        s += x; q += x*x;
    }
    shS[t] = s; shQ[t] = q;
    __syncthreads();
    if (t < 128) {
        atomicAdd(&ws[OFF_SUMH + t], shS[t] + shS[t+128]);
        atomicAdd(&ws[OFF_SQH  + t], shQ[t] + shQ[t+128]);
    }
}

// ---------------- K2: per-edge interval idx + occ + deg ---------------------
__global__ __launch_bounds__(256)
void k_edge_idx(const float* __restrict__ ea, const int* __restrict__ edges,
                float* __restrict__ ws) {
    __shared__ int locc[NIV];
    __shared__ float bps[32];
    __shared__ int sm;
    int* wsi = (int*)ws;
    int t = threadIdx.x;
    if (t < NIV) locc[t] = 0;
    if (t < 32)  bps[t] = ws[OFF_BPS + t];
    if (t == 0)  sm = wsi[OFF_M];
    __syncthreads();
    int m = sm;
    for (int e = blockIdx.x*blockDim.x + t; e < E_; e += gridDim.x*blockDim.x) {
        float a = ea[e];
        int cnt = 0;
        for (int k = 0; k < m; ++k) cnt += (bps[k] < a) ? 1 : 0;
        wsi[OFF_IDX + e] = cnt;
        atomicAdd(&locc[cnt], 1);
        atomicAdd(&wsi[OFF_DEG + edges[E_ + e]], 1);  // node_in histogram
    }
    __syncthreads();
    if (t < NIV && locc[t] > 0) atomicAdd(&wsi[OFF_OCC + t], locc[t]);
}

// ---------------- K3: P = relu(bn(H)) @ w1.T + b1 ---------------------------
__global__ __launch_bounds__(256)
void k_nodeP(const float* __restrict__ H, const float* __restrict__ w1,
             const float* __restrict__ b1, const float* __restrict__ g_in,
             const float* __restrict__ beta_in, float* __restrict__ ws) {
    __shared__ float X[2][IND];
    __shared__ float shP[256];
    int t = threadIdx.x;
    int nh = t >> 7, c = t & 127;
    float mean = ws[OFF_SUMH + c] * (1.f/N_);
    float var  = ws[OFF_SQH  + c] * (1.f/N_) - mean*mean;
    float istd = 1.f / sqrtf(var + EPS);
    float gc = g_in[c] * istd, bc = beta_in[c] - mean * gc;
    int j = c & 31, qd = c >> 5;
    for (int base = blockIdx.x*2; base < N_; base += gridDim.x*2) {
        int n = base + nh;
        float x = H[(size_t)n*IND + c];
        X[nh][c] = fmaxf(gc*x + bc, 0.f);
        __syncthreads();
        float part = 0.f;
        const float* wrow = w1 + j*IND + qd*32;
        const float* xq   = &X[nh][qd*32];
        for (int k = 0; k < 32; ++k) part += wrow[k] * xq[k];
        shP[t] = part;
        __syncthreads();
        if (c < 32) {
            float p = shP[nh*128 + j] + shP[nh*128 + j + 32]
                    + shP[nh*128 + j + 64] + shP[nh*128 + j + 96] + b1[j];
            ws[OFF_P + (size_t)n*HID + j] = p;
        }
        __syncthreads();
    }
}

// ---------------- K4: degree-weighted stats of P (== stats of msg over E) ---
__global__ __launch_bounds__(256)
void k_msg_stats(float* __restrict__ ws) {
    __shared__ float shS[256], shQ[256];
    const int* wsi = (const int*)ws;
    int t = threadIdx.x, j = t & 31, cp = t >> 5;
    float s = 0.f, q = 0.f;
    for (int n = blockIdx.x*8 + cp; n < N_; n += gridDim.x*8) {
        float w = (float)wsi[OFF_DEG + n];
        float p = ws[OFF_P + (size_t)n*HID + j];
        s += w*p; q += w*p*p;
    }
    shS[t] = s; shQ[t] = q;
    __syncthreads();
    if (t < 32) {
        float S = 0.f, Qq = 0.f;
        for (int c = 0; c < 8; ++c) { S += shS[t + 32*c]; Qq += shQ[t + 32*c]; }
        atomicAdd(&ws[OFF_SUMP + t], S);
        atomicAdd(&ws[OFF_SQP  + t], Qq);
    }
}

// ---------------- K5: Q = relu(bn(P)); per-node-per-slot yy tables ----------
__global__ __launch_bounds__(256)
void k_Qy(const float* __restrict__ g_msg, const float* __restrict__ beta_msg,
          float* __restrict__ ws, int max_slots) {
    __shared__ float QL[8][HID];
    __shared__ int inv_slot[NIV];
    __shared__ int nslot;
    const int* wsi = (const int*)ws;
    int t = threadIdx.x, ln = t >> 5, j = t & 31;
    if (t == 0) {
        int ns = 0;
        for (int i = 0; i < NIV; ++i)
            if (wsi[OFF_OCC + i] > 0 && ns < max_slots) inv_slot[ns++] = i;
        nslot = ns;
    }
    __syncthreads();
    int ns = nslot;
    float mP = ws[OFF_SUMP + j] * (1.f/E_);
    float vP = ws[OFF_SQP  + j] * (1.f/E_) - mP*mP;
    float istd = 1.f / sqrtf(vP + EPS);
    float gc = g_msg[j]*istd, bc = beta_msg[j] - mP*gc;
    float2* yy = (float2*)(ws + OFF_Y);
    for (int base = blockIdx.x*8; base < N_; base += gridDim.x*8) {
        int n = base + ln;
        float p = ws[OFF_P + (size_t)n*HID + j];
        float qv = fmaxf(gc*p + bc, 0.f);
        ws[OFF_Q + (size_t)n*HID + j] = qv;
        QL[ln][j] = qv;
        __syncthreads();
        for (int s = 0; s < ns; ++s) {
            int i = inv_slot[s];
            const float* C1r = ws + OFF_C1 + (size_t)i*1056;
            const float* C0r = ws + OFF_C0 + (size_t)i*1056;
            float a1 = 0.f, a0 = 0.f;
            const float* ql = QL[ln];
            for (int k = 0; k < 32; ++k) {
                float qk = ql[k];
                a1 += C1r[32 + j*32 + k] * qk;
                a0 += C0r[32 + j*32 + k] * qk;
            }
            yy[((size_t)s*N_ + n)*32 + j] = make_float2(a1 + C1r[j], a0 + C0r[j]);
        }
        __syncthreads();
    }
}

// ---------------- K6: per-edge evaluate + scatter-add into upd --------------
__global__ __launch_bounds__(256)
void k_edge(const float* __restrict__ ea, const int* __restrict__ edges,
            float* __restrict__ ws, int max_slots) {
    __shared__ int slotL[NIV];
    const int* wsi = (const int*)ws;
    int t = threadIdx.x;
    if (t == 0) {
        int ns = 0;
        for (int i = 0; i < NIV; ++i) {
            if (wsi[OFF_OCC + i] > 0 && ns < max_slots) slotL[i] = ns++;
            else slotL[i] = -1;
        }
    }
    __syncthreads();
    long long g = (long long)blockIdx.x*blockDim.x + t;
    if (g >= (long long)E_*32) return;
    int e = (int)(g >> 5), j = (int)(g & 31);
    float a = ea[e];
    int i   = wsi[OFF_IDX + e];
    int s   = slotL[i];
    int nin = edges[E_ + e], nout = edges[e];
    float r;
    if (s >= 0) {
        const float2* yy = (const float2*)(ws + OFF_Y);
        float2 v = yy[((size_t)s*N_ + nin)*32 + j];
        r = fmaf(a, v.x, v.y);
    } else {   // general fallback (never taken with the given inputs)
        const float* C1r = ws + OFF_C1 + (size_t)i*1056;
        const float* C0r = ws + OFF_C0 + (size_t)i*1056;
        const float* Qn  = ws + OFF_Q + (size_t)nin*HID;
        float a1 = 0.f, a0 = 0.f;
        for (int k = 0; k < 32; ++k) {
            float qk = Qn[k];
            a1 += C1r[32 + j*32 + k] * qk;
            a0 += C0r[32 + j*32 + k] * qk;
        }
        r = a*(a1 + C1r[j]) + (a0 + C0r[j]);
    }
    atomicAdd(&ws[OFF_UPD + (size_t)nout*HID + j], r);
}

// ---------------- K7: stats of upd ------------------------------------------
__global__ __launch_bounds__(256)
void k_upd_stats(float* __restrict__ ws) {
    __shared__ float shS[256], shQ[256];
    int t = threadIdx.x, j = t & 31, cp = t >> 5;
    float s = 0.f, q = 0.f;
    for (int n = blockIdx.x*8 + cp; n < N_; n += gridDim.x*8) {
        float u = ws[OFF_UPD + (size_t)n*HID + j];
        s += u; q += u*u;
    }
    shS[t] = s; shQ[t] = q;
    __syncthreads();
    if (t < 32) {
        float S = 0.f, Qq = 0.f;
        for (int c = 0; c < 8; ++c) { S += shS[t + 32*c]; Qq += shQ[t + 32*c]; }
        atomicAdd(&ws[OFF_SUMU + t], S);
        atomicAdd(&ws[OFF_SQU  + t], Qq);
    }
}

// ---------------- K8: out_pre = relu(bn(upd)) @ w2.T + b2 ; out stats -------
__global__ __launch_bounds__(256)
void k_out(const float* __restrict__ w2, const float* __restrict__ b2,
           const float* __restrict__ g_upd, const float* __restrict__ beta_upd,
           float* __restrict__ ws, float* __restrict__ out) {
    __shared__ float U[2][HID];
    __shared__ float shS[256], shQ[256];
    int t = threadIdx.x, nh = t >> 7, o = t & 127;
    float gc = 0.f, bc = 0.f;
    if (o < 32) {
        float m = ws[OFF_SUMU + o]*(1.f/N_);
        float v = ws[OFF_SQU  + o]*(1.f/N_) - m*m;
        float istd = 1.f/sqrtf(v + EPS);
        gc = g_upd[o]*istd; bc = beta_upd[o] - m*gc;
    }
    float w2r[32];
    for (int k = 0; k < 32; ++k) w2r[k] = w2[o*32 + k];
    float bo = b2[o];
    float sO = 0.f, qO = 0.f;
    for (int base = blockIdx.x*2; base < N_; base += gridDim.x*2) {
        int n = base + nh;
        if (o < 32) {
            float u = ws[OFF_UPD + (size_t)n*HID + o];
            U[nh][o] = fmaxf(gc*u + bc, 0.f);
        }
        __syncthreads();
        float v = bo;
        for (int k = 0; k < 32; ++k) v += w2r[k]*U[nh][k];
        out[(size_t)n*OUTD + o] = v;
        sO += v; qO += v*v;
        __syncthreads();
    }
    shS[t] = sO; shQ[t] = qO;
    __syncthreads();
    if (t < 128) {
        atomicAdd(&ws[OFF_SUMO + t], shS[t] + shS[t+128]);
        atomicAdd(&ws[OFF_SQO  + t], shQ[t] + shQ[t+128]);
    }
}

// ---------------- K9: final output batch-norm (in-place) --------------------
__global__ __launch_bounds__(256)
void k_norm(const float* __restrict__ g_out, const float* __restrict__ beta_out,
            const float* __restrict__ ws, float* __restrict__ out) {
    int g = blockIdx.x*blockDim.x + threadIdx.x;
    if (g >= N_*OUTD) return;
    int o = g & 127;
    float m = ws[OFF_SUMO + o]*(1.f/N_);
    float v = ws[OFF_SQO  + o]*(1.f/N_) - m*m;
    float istd = 1.f/sqrtf(v + EPS);
    out[g] = g_out[o]*istd*(out[g] - m) + beta_out[o];
}

// ---------------- launch -----------------------------------------------------
extern "C" void kernel_launch(void* const* d_in, const int* in_sizes, int n_in,
                              void* d_out, int out_size, void* d_ws, size_t ws_size,
                              hipStream_t stream) {
    const float* H        = (const float*)d_in[0];
    const float* ea       = (const float*)d_in[1];
    const int*   edges    = (const int*)  d_in[2];
    const float* w1       = (const float*)d_in[3];
    const float* b1       = (const float*)d_in[4];
    const float* kw1      = (const float*)d_in[5];
    const float* kb1      = (const float*)d_in[6];
    const float* kw2      = (const float*)d_in[7];
    const float* kb2      = (const float*)d_in[8];
    const float* w2       = (const float*)d_in[9];
    const float* b2       = (const float*)d_in[10];
    const float* g_in     = (const float*)d_in[11];
    const float* beta_in  = (const float*)d_in[12];
    const float* g_msg    = (const float*)d_in[13];
    const float* beta_msg = (const float*)d_in[14];
    const float* g_upd    = (const float*)d_in[15];
    const float* beta_upd = (const float*)d_in[16];
    const float* g_out    = (const float*)d_in[17];
    const float* beta_out = (const float*)d_in[18];
    float* ws  = (float*)d_ws;
    float* out = (float*)d_out;

    int max_slots = 0;
    size_t avail = ws_size / 4;
    if (avail > OFF_Y) max_slots = (int)((avail - OFF_Y) / ((size_t)N_*2*HID));
    if (max_slots > NIV) max_slots = NIV;

    hipMemsetAsync(d_ws, 0, ZERO_CNT*sizeof(float), stream);
    hipLaunchKernelGGL(k_intervals, dim3(NIV), dim3(128), 0, stream, kw1, kb1, kw2, kb2, ws);
    hipLaunchKernelGGL(k_stats_H,  dim3(128),  dim3(256), 0, stream, H, ws);
    hipLaunchKernelGGL(k_edge_idx, dim3(313),  dim3(256), 0, stream, ea, edges, ws);
    hipLaunchKernelGGL(k_nodeP,    dim3(1250), dim3(256), 0, stream, H, w1, b1, g_in, beta_in, ws);
    hipLaunchKernelGGL(k_msg_stats,dim3(64),   dim3(256), 0, stream, ws);
    hipLaunchKernelGGL(k_Qy,       dim3(1250), dim3(256), 0, stream, g_msg, beta_msg, ws, max_slots);
    hipLaunchKernelGGL(k_edge,     dim3((E_*32)/256), dim3(256), 0, stream, ea, edges, ws, max_slots);
    hipLaunchKernelGGL(k_upd_stats,dim3(64),   dim3(256), 0, stream, ws);
    hipLaunchKernelGGL(k_out,      dim3(250),  dim3(256), 0, stream, w2, b2, g_upd, beta_upd, ws, out);
    hipLaunchKernelGGL(k_norm,     dim3((N_*OUTD+255)/256), dim3(256), 0, stream, g_out, beta_out, ws, out);
}

// Round 3
// 298.172 us; speedup vs baseline: 1.0434x; 1.0434x over previous
//
#include <hip/hip_runtime.h>
#include <math.h>

// ---------------- problem constants ----------------
constexpr int N_    = 10000;
constexpr int E_    = 320000;
constexpr int IND   = 128;
constexpr int HID   = 32;
constexpr int OUTD  = 128;
constexpr int NIV   = 33;      // max intervals = 32 breakpoints + 1
constexpr float EPS = 1e-5f;

// ---------------- workspace layout (element offsets, 4B each) ----
constexpr size_t OFF_SUMH   = 0;       // 128 f
constexpr size_t OFF_SQH    = 128;     // 128 f
constexpr size_t OFF_SUMP   = 256;     // 32 f
constexpr size_t OFF_SQP    = 288;     // 32 f
constexpr size_t OFF_SUMU   = 320;     // 32 f
constexpr size_t OFF_SQU    = 352;     // 32 f
constexpr size_t OFF_SUMO   = 384;     // 128 f
constexpr size_t OFF_SQO    = 512;     // 128 f
constexpr size_t OFF_OCC    = 640;     // 33 i
constexpr size_t OFF_DEGIN  = 704;     // 10000 i
constexpr size_t OFF_DEGOUT = 10704;   // 10000 i
constexpr size_t ZERO_CNT   = 20704;   // elements zeroed by memset
constexpr size_t OFF_STARTS = 20740;   // 10001 i  CSR row starts
constexpr size_t OFF_CUR    = 30744;   // 10000 i  scatter cursors
constexpr size_t OFF_C1     = 40744;   // 33*1056 f
constexpr size_t OFF_C0     = 75592;   // 33*1056 f
constexpr size_t OFF_P      = 110440;  // N*32 f (16B aligned)
constexpr size_t OFF_UPD    = 430440;  // N*32 f
constexpr size_t OFF_SORT   = 750440;  // E i
constexpr size_t OFF_IDX    = 1070440; // E i
// total 1390440 elems = 5.56 MB

// helper: compute sorted breakpoints of relu(a*kw1+kb1) — device function,
// called independently wherever needed (NO cross-block data dependence).
__device__ inline int compute_bps(const float* kw1, const float* kb1, float* bp) {
    int m = 0;
    for (int k = 0; k < 32; ++k) {
        float w = kw1[k];
        if (w != 0.f) bp[m++] = -kb1[k] / w;
    }
    for (int a = 1; a < m; ++a) {
        float v = bp[a]; int b = a - 1;
        while (b >= 0 && bp[b] > v) { bp[b+1] = bp[b]; --b; }
        bp[b+1] = v;
    }
    return m;
}

// =======================================================================
// K_A (fused): blocks [0,33) interval tables | [33,161) H stats |
//              [161,474) per-edge interval idx + occ + in/out degree
// NOTE: every branch is self-sufficient (recomputes breakpoints locally);
// blocks of one dispatch run concurrently with NO ordering/coherence.
// =======================================================================
__global__ __launch_bounds__(256)
void k_A(const float* __restrict__ H,
         const float* __restrict__ ea, const int* __restrict__ edges,
         const float* __restrict__ kw1, const float* __restrict__ kb1,
         const float* __restrict__ kw2, const float* __restrict__ kb2,
         float* __restrict__ ws) {
    __shared__ float sel1[32], sel0[32];
    __shared__ float shS[256], shQ[256];
    __shared__ int locc[NIV];
    __shared__ float bps[32];
    __shared__ int sm;
    int* wsi = (int*)ws;
    int t = threadIdx.x;
    int bid = blockIdx.x;

    if (bid < 33) {
        // ---- interval tables ----
        int i = bid;
        if (t == 0) {
            float bp[32];
            int m = compute_bps(kw1, kb1, bp);
            float arep;
            if (m == 0 || i > m) arep = 0.f;
            else if (i == 0)     arep = bp[0]   - (1.f + 0.5f*fabsf(bp[0]));
            else if (i == m)     arep = bp[m-1] + (1.f + 0.5f*fabsf(bp[m-1]));
            else                 arep = (bp[i-1] < bp[i]) ? 0.5f*(bp[i-1] + bp[i]) : bp[i-1];
            for (int k = 0; k < 32; ++k) {
                bool s = (arep * kw1[k] + kb1[k]) > 0.f;
                sel1[k] = s ? kw1[k] : 0.f;
                sel0[k] = s ? kb1[k] : 0.f;
            }
        }
        __syncthreads();
        for (int r = t; r < 1056; r += 256) {
            float a1 = 0.f, a0 = 0.f;
            for (int k = 0; k < 32; ++k) {
                float w = kw2[r*32 + k];
                a1 += w * sel1[k];
                a0 += w * sel0[k];
            }
            ws[OFF_C1 + (size_t)i*1056 + r] = a1;
            ws[OFF_C0 + (size_t)i*1056 + r] = a0 + kb2[r];
        }
    } else if (bid < 161) {
        // ---- column stats of H ----
        int b2 = bid - 33;
        int col = t & 127, half = t >> 7;
        float s = 0.f, q = 0.f;
        for (int r = b2*2 + half; r < N_; r += 128*2) {
            float x = H[(size_t)r*IND + col];
            s += x; q += x*x;
        }
        shS[t] = s; shQ[t] = q;
        __syncthreads();
        if (t < 128) {
            atomicAdd(&ws[OFF_SUMH + t], shS[t] + shS[t+128]);
            atomicAdd(&ws[OFF_SQH  + t], shQ[t] + shQ[t+128]);
        }
    } else {
        // ---- per-edge interval idx + occ + degrees ----
        // breakpoints computed LOCALLY (fix for R2 cross-block race)
        int b2 = bid - 161;
        if (t < NIV) locc[t] = 0;
        if (t == 0) {
            float bp[32];
            int m = compute_bps(kw1, kb1, bp);
            for (int k = 0; k < 32; ++k) bps[k] = (k < m) ? bp[k] : 0.f;
            sm = m;
        }
        __syncthreads();
        int m = sm;
        for (int e = b2*256 + t; e < E_; e += 313*256) {
            float a = ea[e];
            int cnt = 0;
            for (int k = 0; k < m; ++k) cnt += (bps[k] < a) ? 1 : 0;
            wsi[OFF_IDX + e] = cnt;
            atomicAdd(&locc[cnt], 1);
            atomicAdd(&wsi[OFF_DEGIN  + edges[E_ + e]], 1);
            atomicAdd(&wsi[OFF_DEGOUT + edges[e]],      1);
        }
        __syncthreads();
        if (t < NIV && locc[t] > 0) atomicAdd(&wsi[OFF_OCC + t], locc[t]);
    }
}

// =======================================================================
// K_B (fused): block 0 = exclusive scan of out-degree -> starts/cur
//              blocks 1..1250 = P = relu(bn_in(H)) @ w1.T + b1
// =======================================================================
__global__ __launch_bounds__(256)
void k_B(const float* __restrict__ H, const float* __restrict__ w1,
         const float* __restrict__ b1, const float* __restrict__ g_in,
         const float* __restrict__ beta_in, float* __restrict__ ws) {
    __shared__ float w1L[32*129];
    __shared__ float xl[8][128];
    __shared__ int part[256];
    int* wsi = (int*)ws;
    int t = threadIdx.x;

    if (blockIdx.x == 0) {
        // ---- exclusive scan of DEGOUT over 10001 entries ----
        int base = t * 40;
        int loc[40];
        int s = 0;
        for (int i = 0; i < 40; ++i) {
            int idx = base + i;
            int v = (idx < N_) ? wsi[OFF_DEGOUT + idx] : 0;
            loc[i] = s; s += v;
        }
        part[t] = s;
        __syncthreads();
        for (int off = 1; off < 256; off <<= 1) {
            int add = (t >= off) ? part[t - off] : 0;
            __syncthreads();
            part[t] += add;
            __syncthreads();
        }
        int pre = (t > 0) ? part[t-1] : 0;
        for (int i = 0; i < 40; ++i) {
            int idx = base + i;
            if (idx <= N_) {
                int v = pre + loc[i];
                wsi[OFF_STARTS + idx] = v;
                if (idx < N_) wsi[OFF_CUR + idx] = v;
            }
        }
        return;
    }

    // ---- nodeP: 8 nodes per block, 32 threads per node ----
    int g = t >> 5, j = t & 31;
    for (int idx = t; idx < 4096; idx += 256)
        w1L[(idx >> 7)*129 + (idx & 127)] = w1[idx];

    int n = (blockIdx.x - 1)*8 + g;
    float4 h4 = ((const float4*)(H + (size_t)n*IND))[j];
    float4 m4 = ((const float4*)(ws + OFF_SUMH))[j];
    float4 q4 = ((const float4*)(ws + OFF_SQH))[j];
    float4 gg = ((const float4*)g_in)[j];
    float4 bb = ((const float4*)beta_in)[j];
    float4 xv;
    {
        float* hp = (float*)&h4; float* mp = (float*)&m4; float* qp = (float*)&q4;
        float* gp = (float*)&gg; float* bp = (float*)&bb; float* xp = (float*)&xv;
        for (int i = 0; i < 4; ++i) {
            float mean = mp[i] * (1.f/N_);
            float var  = qp[i] * (1.f/N_) - mean*mean;
            float istd = 1.f / sqrtf(var + EPS);
            float gc = gp[i]*istd, bc = bp[i] - mean*gc;
            xp[i] = fmaxf(fmaf(gc, hp[i], bc), 0.f);
        }
    }
    ((float4*)&xl[g][0])[j] = xv;
    __syncthreads();
    float p = b1[j];
    const float* wr = &w1L[j*129];
    const float* xr = &xl[g][0];
    #pragma unroll 8
    for (int k = 0; k < 128; ++k) p = fmaf(wr[k], xr[k], p);
    ws[OFF_P + (size_t)n*HID + j] = p;
}

// =======================================================================
// K_C (fused): blocks [0,313) scatter edge ids into CSR |
//              [313,377) degree-weighted stats of P (= msg stats over E)
// =======================================================================
__global__ __launch_bounds__(256)
void k_C(const int* __restrict__ edges, float* __restrict__ ws) {
    __shared__ float shS[256], shQ[256];
    int* wsi = (int*)ws;
    int t = threadIdx.x;
    if (blockIdx.x < 313) {
        int b2 = blockIdx.x;
        for (int e = b2*256 + t; e < E_; e += 313*256) {
            int nout = edges[e];
            int pos = atomicAdd(&wsi[OFF_CUR + nout], 1);
            wsi[OFF_SORT + pos] = e;
        }
    } else {
        int b2 = blockIdx.x - 313;
        int j = t & 31, cp = t >> 5;
        float s = 0.f, q = 0.f;
        for (int n = b2*8 + cp; n < N_; n += 64*8) {
            float w = (float)wsi[OFF_DEGIN + n];
            float p = ws[OFF_P + (size_t)n*HID + j];
            s += w*p; q += w*p*p;
        }
        shS[t] = s; shQ[t] = q;
        __syncthreads();
        if (t < 32) {
            float S = 0.f, Qq = 0.f;
            for (int c = 0; c < 8; ++c) { S += shS[t + 32*c]; Qq += shQ[t + 32*c]; }
            atomicAdd(&ws[OFF_SUMP + t], S);
            atomicAdd(&ws[OFF_SQP  + t], Qq);
        }
    }
}

// =======================================================================
// K_D: segment reduce (no atomics on upd) + fused upd stats
//   per node: aggregate Za_s = sum a*Q[nin], Zb_s = sum Q[nin] over its
//   edges (slot s = interval), then one 32x32 matvec per slot from LDS.
// =======================================================================
__global__ __launch_bounds__(256)
void k_D(const float* __restrict__ ea, const int* __restrict__ edges,
         const float* __restrict__ g_msg, const float* __restrict__ beta_msg,
         float* __restrict__ ws) {
    __shared__ float A[4][32*33];   // A1_s0, A0_s0, A1_s1, A0_s1 (padded rows)
    __shared__ float Bv[4][32];     // bias rows
    __shared__ float zl[8][4][32];
    __shared__ float shS[256], shQ[256];
    __shared__ int s_slot0, s_slot1;
    int* wsi = (int*)ws;
    int t = threadIdx.x, g = t >> 5, j = t & 31;

    if (t == 0) {
        int a0 = -1, a1 = -1;
        for (int i = 0; i < NIV; ++i)
            if (wsi[OFF_OCC + i] > 0) { if (a0 < 0) a0 = i; else if (a1 < 0) a1 = i; }
        s_slot0 = a0; s_slot1 = a1;
    }
    __syncthreads();
    int s0 = s_slot0, s1 = s_slot1;

    for (int idx = t; idx < 1024; idx += 256) {
        int jj = idx >> 5, kk = idx & 31;
        A[0][jj*33+kk] = (s0 >= 0) ? ws[OFF_C1 + (size_t)s0*1056 + 32 + idx] : 0.f;
        A[1][jj*33+kk] = (s0 >= 0) ? ws[OFF_C0 + (size_t)s0*1056 + 32 + idx] : 0.f;
        A[2][jj*33+kk] = (s1 >= 0) ? ws[OFF_C1 + (size_t)s1*1056 + 32 + idx] : 0.f;
        A[3][jj*33+kk] = (s1 >= 0) ? ws[OFF_C0 + (size_t)s1*1056 + 32 + idx] : 0.f;
    }
    if (t < 32) {
        Bv[0][t] = (s0 >= 0) ? ws[OFF_C1 + (size_t)s0*1056 + t] : 0.f;
        Bv[1][t] = (s0 >= 0) ? ws[OFF_C0 + (size_t)s0*1056 + t] : 0.f;
        Bv[2][t] = (s1 >= 0) ? ws[OFF_C1 + (size_t)s1*1056 + t] : 0.f;
        Bv[3][t] = (s1 >= 0) ? ws[OFF_C0 + (size_t)s1*1056 + t] : 0.f;
    }
    // bn_msg constants for column j
    float mP = ws[OFF_SUMP + j] * (1.f/E_);
    float vP = ws[OFF_SQP  + j] * (1.f/E_) - mP*mP;
    float istd = 1.f / sqrtf(vP + EPS);
    float gc = g_msg[j]*istd, bc = beta_msg[j] - mP*gc;
    __syncthreads();

    int n = blockIdx.x*8 + g;
    int st = wsi[OFF_STARTS + n], en = wsi[OFF_STARTS + n + 1];
    float za0 = 0.f, zb0 = 0.f, za1 = 0.f, zb1 = 0.f;
    float suma0 = 0.f, suma1 = 0.f, rfall = 0.f;
    int c0 = 0, c1 = 0;
    for (int p = st; p < en; ++p) {
        int e   = wsi[OFF_SORT + p];
        float a = ea[e];
        int iv  = wsi[OFF_IDX + e];
        int nin = edges[E_ + e];
        float pv = ws[OFF_P + (size_t)nin*HID + j];
        float q  = fmaxf(fmaf(gc, pv, bc), 0.f);
        if (iv == s0)      { za0 = fmaf(a, q, za0); zb0 += q; suma0 += a; ++c0; }
        else if (iv == s1) { za1 = fmaf(a, q, za1); zb1 += q; suma1 += a; ++c1; }
        else {  // general fallback (not taken with given inputs)
            const float* C1r = ws + OFF_C1 + (size_t)iv*1056;
            const float* C0r = ws + OFF_C0 + (size_t)iv*1056;
            float d1 = 0.f, d0 = 0.f;
            for (int k = 0; k < 32; ++k) {
                float qk = __shfl(q, k, 32);
                d1 += C1r[32 + j*32 + k] * qk;
                d0 += C0r[32 + j*32 + k] * qk;
            }
            rfall += a*(d1 + C1r[j]) + (d0 + C0r[j]);
        }
    }
    zl[g][0][j] = za0; zl[g][1][j] = zb0; zl[g][2][j] = za1; zl[g][3][j] = zb1;
    __syncthreads();

    float acc = rfall;
    if (s0 >= 0) acc += suma0*Bv[0][j] + (float)c0*Bv[1][j];
    if (s1 >= 0) acc += suma1*Bv[2][j] + (float)c1*Bv[3][j];
    const float* z0 = zl[g][0]; const float* z1 = zl[g][1];
    const float* z2 = zl[g][2]; const float* z3 = zl[g][3];
    #pragma unroll 4
    for (int k = 0; k < 32; ++k) {
        acc += A[0][j*33+k]*z0[k] + A[1][j*33+k]*z1[k]
             + A[2][j*33+k]*z2[k] + A[3][j*33+k]*z3[k];
    }
    ws[OFF_UPD + (size_t)n*HID + j] = acc;

    // fused upd stats
    shS[t] = acc; shQ[t] = acc*acc;
    __syncthreads();
    if (t < 32) {
        float S = 0.f, Qq = 0.f;
        for (int c = 0; c < 8; ++c) { S += shS[t + 32*c]; Qq += shQ[t + 32*c]; }
        atomicAdd(&ws[OFF_SUMU + t], S);
        atomicAdd(&ws[OFF_SQU  + t], Qq);
    }
}

// =======================================================================
// K_F: out_pre = relu(bn(upd)) @ w2.T + b2 ; accumulate out stats
// =======================================================================
__global__ __launch_bounds__(256)
void k_F(const float* __restrict__ w2, const float* __restrict__ b2,
         const float* __restrict__ g_upd, const float* __restrict__ beta_upd,
         float* __restrict__ ws, float* __restrict__ out) {
    __shared__ float U[2][HID];
    __shared__ float shS[256], shQ[256];
    int t = threadIdx.x, nh = t >> 7, o = t & 127;
    float gc = 0.f, bc = 0.f;
    if (o < 32) {
        float m = ws[OFF_SUMU + o]*(1.f/N_);
        float v = ws[OFF_SQU  + o]*(1.f/N_) - m*m;
        float istd = 1.f/sqrtf(v + EPS);
        gc = g_upd[o]*istd; bc = beta_upd[o] - m*gc;
    }
    float w2r[32];
    for (int k = 0; k < 32; ++k) w2r[k] = w2[o*32 + k];
    float bo = b2[o];
    float sO = 0.f, qO = 0.f;
    for (int base = blockIdx.x*2; base < N_; base += gridDim.x*2) {
        int n = base + nh;
        if (o < 32) {
            float u = ws[OFF_UPD + (size_t)n*HID + o];
            U[nh][o] = fmaxf(fmaf(gc, u, bc), 0.f);
        }
        __syncthreads();
        float v = bo;
        for (int k = 0; k < 32; ++k) v = fmaf(w2r[k], U[nh][k], v);
        out[(size_t)n*OUTD + o] = v;
        sO += v; qO += v*v;
        __syncthreads();
    }
    shS[t] = sO; shQ[t] = qO;
    __syncthreads();
    if (t < 128) {
        atomicAdd(&ws[OFF_SUMO + t], shS[t] + shS[t+128]);
        atomicAdd(&ws[OFF_SQO  + t], shQ[t] + shQ[t+128]);
    }
}

// =======================================================================
// K_G: final output batch-norm (in-place)
// =======================================================================
__global__ __launch_bounds__(256)
void k_G(const float* __restrict__ g_out, const float* __restrict__ beta_out,
         const float* __restrict__ ws, float* __restrict__ out) {
    int g = blockIdx.x*blockDim.x + threadIdx.x;
    if (g >= N_*OUTD) return;
    int o = g & 127;
    float m = ws[OFF_SUMO + o]*(1.f/N_);
    float v = ws[OFF_SQO  + o]*(1.f/N_) - m*m;
    float istd = 1.f/sqrtf(v + EPS);
    out[g] = g_out[o]*istd*(out[g] - m) + beta_out[o];
}

// ---------------- launch -----------------------------------------------------
extern "C" void kernel_launch(void* const* d_in, const int* in_sizes, int n_in,
                              void* d_out, int out_size, void* d_ws, size_t ws_size,
                              hipStream_t stream) {
    const float* H        = (const float*)d_in[0];
    const float* ea       = (const float*)d_in[1];
    const int*   edges    = (const int*)  d_in[2];
    const float* w1       = (const float*)d_in[3];
    const float* b1       = (const float*)d_in[4];
    const float* kw1      = (const float*)d_in[5];
    const float* kb1      = (const float*)d_in[6];
    const float* kw2      = (const float*)d_in[7];
    const float* kb2      = (const float*)d_in[8];
    const float* w2       = (const float*)d_in[9];
    const float* b2       = (const float*)d_in[10];
    const float* g_in     = (const float*)d_in[11];
    const float* beta_in  = (const float*)d_in[12];
    const float* g_msg    = (const float*)d_in[13];
    const float* beta_msg = (const float*)d_in[14];
    const float* g_upd    = (const float*)d_in[15];
    const float* beta_upd = (const float*)d_in[16];
    const float* g_out    = (const float*)d_in[17];
    const float* beta_out = (const float*)d_in[18];
    float* ws  = (float*)d_ws;
    float* out = (float*)d_out;

    hipMemsetAsync(d_ws, 0, ZERO_CNT*sizeof(float), stream);
    hipLaunchKernelGGL(k_A, dim3(474),  dim3(256), 0, stream, H, ea, edges, kw1, kb1, kw2, kb2, ws);
    hipLaunchKernelGGL(k_B, dim3(1251), dim3(256), 0, stream, H, w1, b1, g_in, beta_in, ws);
    hipLaunchKernelGGL(k_C, dim3(377),  dim3(256), 0, stream, edges, ws);
    hipLaunchKernelGGL(k_D, dim3(1250), dim3(256), 0, stream, ea, edges, g_msg, beta_msg, ws);
    hipLaunchKernelGGL(k_F, dim3(250),  dim3(256), 0, stream, w2, b2, g_upd, beta_upd, ws, out);
    hipLaunchKernelGGL(k_G, dim3((N_*OUTD + 255)/256), dim3(256), 0, stream, g_out, beta_out, ws, out);
}

// Round 4
// 257.942 us; speedup vs baseline: 1.2062x; 1.1560x over previous
//
#include <hip/hip_runtime.h>
#include <math.h>

// ---------------- problem constants ----------------
constexpr int N_    = 10000;
constexpr int E_    = 320000;
constexpr int IND   = 128;
constexpr int HID   = 32;
constexpr int OUTD  = 128;
constexpr int NIV   = 33;      // max intervals = 32 breakpoints + 1
constexpr float EPS = 1e-5f;

// ---------------- workspace layout (element offsets, 4B each) ----
constexpr size_t OFF_SUMH   = 0;       // 128 f
constexpr size_t OFF_SQH    = 128;     // 128 f
constexpr size_t OFF_SUMP   = 256;     // 32 f
constexpr size_t OFF_SQP    = 288;     // 32 f
constexpr size_t OFF_SUMU   = 320;     // 32 f
constexpr size_t OFF_SQU    = 352;     // 32 f
constexpr size_t OFF_SUMO   = 384;     // 128 f
constexpr size_t OFF_SQO    = 512;     // 128 f
constexpr size_t OFF_OCC    = 640;     // 33 i
constexpr size_t OFF_DEGIN  = 704;     // 10000 i
constexpr size_t OFF_DEGOUT = 10704;   // 10000 i
constexpr size_t ZERO_CNT   = 20704;   // elements zeroed by memset
constexpr size_t OFF_STARTS = 20740;   // 10001 i  CSR row starts
constexpr size_t OFF_CUR    = 30744;   // 10000 i  scatter cursors
constexpr size_t OFF_C1     = 40744;   // 33*1056 f
constexpr size_t OFF_C0     = 75592;   // 33*1056 f
constexpr size_t OFF_P      = 110440;  // N*32 f (16B aligned)
constexpr size_t OFF_UPD    = 430440;  // N*32 f
constexpr size_t OFF_AEN    = 750440;  // E float2 records {a, nin|(iv<<16)} in CSR order
// total 750440 + 640000 = 1390440 elems = 5.56 MB

// helper: sorted breakpoints of relu(a*kw1+kb1) — recomputed locally wherever
// needed (NO cross-block data dependence).
__device__ inline int compute_bps(const float* kw1, const float* kb1, float* bp) {
    int m = 0;
    for (int k = 0; k < 32; ++k) {
        float w = kw1[k];
        if (w != 0.f) bp[m++] = -kb1[k] / w;
    }
    for (int a = 1; a < m; ++a) {
        float v = bp[a]; int b = a - 1;
        while (b >= 0 && bp[b] > v) { bp[b+1] = bp[b]; --b; }
        bp[b+1] = v;
    }
    return m;
}

// =======================================================================
// K_A (fused): blocks [0,33) interval tables | [33,161) H stats |
//              [161,474) per-edge interval occupancy + in/out degree
// =======================================================================
__global__ __launch_bounds__(256)
void k_A(const float* __restrict__ H,
         const float* __restrict__ ea, const int* __restrict__ edges,
         const float* __restrict__ kw1, const float* __restrict__ kb1,
         const float* __restrict__ kw2, const float* __restrict__ kb2,
         float* __restrict__ ws) {
    __shared__ float sel1[32], sel0[32];
    __shared__ float shS[256], shQ[256];
    __shared__ int locc[NIV];
    __shared__ float bps[32];
    int* wsi = (int*)ws;
    int t = threadIdx.x;
    int bid = blockIdx.x;

    if (bid < 33) {
        // ---- interval tables ----
        int i = bid;
        if (t == 0) {
            float bp[32];
            int m = compute_bps(kw1, kb1, bp);
            float arep;
            if (m == 0 || i > m) arep = 0.f;
            else if (i == 0)     arep = bp[0]   - (1.f + 0.5f*fabsf(bp[0]));
            else if (i == m)     arep = bp[m-1] + (1.f + 0.5f*fabsf(bp[m-1]));
            else                 arep = (bp[i-1] < bp[i]) ? 0.5f*(bp[i-1] + bp[i]) : bp[i-1];
            for (int k = 0; k < 32; ++k) {
                bool s = (arep * kw1[k] + kb1[k]) > 0.f;
                sel1[k] = s ? kw1[k] : 0.f;
                sel0[k] = s ? kb1[k] : 0.f;
            }
        }
        __syncthreads();
        for (int r = t; r < 1056; r += 256) {
            float a1 = 0.f, a0 = 0.f;
            for (int k = 0; k < 32; ++k) {
                float w = kw2[r*32 + k];
                a1 += w * sel1[k];
                a0 += w * sel0[k];
            }
            ws[OFF_C1 + (size_t)i*1056 + r] = a1;
            ws[OFF_C0 + (size_t)i*1056 + r] = a0 + kb2[r];
        }
    } else if (bid < 161) {
        // ---- column stats of H ----
        int b2 = bid - 33;
        int col = t & 127, half = t >> 7;
        float s = 0.f, q = 0.f;
        for (int r = b2*2 + half; r < N_; r += 128*2) {
            float x = H[(size_t)r*IND + col];
            s += x; q += x*x;
        }
        shS[t] = s; shQ[t] = q;
        __syncthreads();
        if (t < 128) {
            atomicAdd(&ws[OFF_SUMH + t], shS[t] + shS[t+128]);
            atomicAdd(&ws[OFF_SQH  + t], shQ[t] + shQ[t+128]);
        }
    } else {
        // ---- per-edge interval occupancy + degrees ----
        int b2 = bid - 161;
        if (t < NIV) locc[t] = 0;
        if (t == 0) {
            float bp[32];
            int m = compute_bps(kw1, kb1, bp);
            for (int k = 0; k < 32; ++k) bps[k] = (k < m) ? bp[k] : 3.0e38f;
        }
        __syncthreads();
        for (int e = b2*256 + t; e < E_; e += 313*256) {
            float a = ea[e];
            int cnt = 0;
            #pragma unroll
            for (int k = 0; k < 32; ++k) cnt += (bps[k] < a) ? 1 : 0;
            atomicAdd(&locc[cnt], 1);
            atomicAdd(&wsi[OFF_DEGIN  + edges[E_ + e]], 1);
            atomicAdd(&wsi[OFF_DEGOUT + edges[e]],      1);
        }
        __syncthreads();
        if (t < NIV && locc[t] > 0) atomicAdd(&wsi[OFF_OCC + t], locc[t]);
    }
}

// =======================================================================
// K_B (fused): block 0 = exclusive scan of out-degree -> starts/cur
//              blocks 1..1250 = P = relu(bn_in(H)) @ w1.T + b1
// =======================================================================
__global__ __launch_bounds__(256)
void k_B(const float* __restrict__ H, const float* __restrict__ w1,
         const float* __restrict__ b1, const float* __restrict__ g_in,
         const float* __restrict__ beta_in, float* __restrict__ ws) {
    __shared__ float w1L[32*129];
    __shared__ float xl[8][128];
    __shared__ int part[256];
    int* wsi = (int*)ws;
    int t = threadIdx.x;

    if (blockIdx.x == 0) {
        // ---- exclusive scan of DEGOUT over 10001 entries ----
        int base = t * 40;
        int loc[40];
        int s = 0;
        for (int i = 0; i < 40; ++i) {
            int idx = base + i;
            int v = (idx < N_) ? wsi[OFF_DEGOUT + idx] : 0;
            loc[i] = s; s += v;
        }
        part[t] = s;
        __syncthreads();
        for (int off = 1; off < 256; off <<= 1) {
            int add = (t >= off) ? part[t - off] : 0;
            __syncthreads();
            part[t] += add;
            __syncthreads();
        }
        int pre = (t > 0) ? part[t-1] : 0;
        for (int i = 0; i < 40; ++i) {
            int idx = base + i;
            if (idx <= N_) {
                int v = pre + loc[i];
                wsi[OFF_STARTS + idx] = v;
                if (idx < N_) wsi[OFF_CUR + idx] = v;
            }
        }
        return;
    }

    // ---- nodeP: 8 nodes per block, 32 threads per node ----
    int g = t >> 5, j = t & 31;
    for (int idx = t; idx < 4096; idx += 256)
        w1L[(idx >> 7)*129 + (idx & 127)] = w1[idx];

    int n = (blockIdx.x - 1)*8 + g;
    float4 h4 = ((const float4*)(H + (size_t)n*IND))[j];
    float4 m4 = ((const float4*)(ws + OFF_SUMH))[j];
    float4 q4 = ((const float4*)(ws + OFF_SQH))[j];
    float4 gg = ((const float4*)g_in)[j];
    float4 bb = ((const float4*)beta_in)[j];
    float4 xv;
    {
        float* hp = (float*)&h4; float* mp = (float*)&m4; float* qp = (float*)&q4;
        float* gp = (float*)&gg; float* bp = (float*)&bb; float* xp = (float*)&xv;
        for (int i = 0; i < 4; ++i) {
            float mean = mp[i] * (1.f/N_);
            float var  = qp[i] * (1.f/N_) - mean*mean;
            float istd = 1.f / sqrtf(var + EPS);
            float gc = gp[i]*istd, bc = bp[i] - mean*gc;
            xp[i] = fmaxf(fmaf(gc, hp[i], bc), 0.f);
        }
    }
    ((float4*)&xl[g][0])[j] = xv;
    __syncthreads();
    float p = b1[j];
    const float* wr = &w1L[j*129];
    const float* xr = &xl[g][0];
    #pragma unroll 8
    for (int k = 0; k < 128; ++k) p = fmaf(wr[k], xr[k], p);
    ws[OFF_P + (size_t)n*HID + j] = p;
}

// =======================================================================
// K_C (fused): blocks [0,313) build CSR-ordered edge records {a, nin|iv<<16} |
//              [313,377) degree-weighted stats of P (= msg stats over E)
// =======================================================================
__global__ __launch_bounds__(256)
void k_C(const float* __restrict__ ea, const int* __restrict__ edges,
         const float* __restrict__ kw1, const float* __restrict__ kb1,
         float* __restrict__ ws) {
    __shared__ float shS[256], shQ[256];
    __shared__ float bps[32];
    int* wsi = (int*)ws;
    int t = threadIdx.x;
    if (blockIdx.x < 313) {
        if (t == 0) {
            float bp[32];
            int m = compute_bps(kw1, kb1, bp);
            for (int k = 0; k < 32; ++k) bps[k] = (k < m) ? bp[k] : 3.0e38f;
        }
        __syncthreads();
        float2* aen = (float2*)(ws + OFF_AEN);
        int b2 = blockIdx.x;
        for (int e = b2*256 + t; e < E_; e += 313*256) {
            int   nout = edges[e];
            int   nin  = edges[E_ + e];
            float a    = ea[e];
            int iv = 0;
            #pragma unroll
            for (int k = 0; k < 32; ++k) iv += (bps[k] < a) ? 1 : 0;
            int pos = atomicAdd(&wsi[OFF_CUR + nout], 1);
            float2 rec; rec.x = a; rec.y = __int_as_float(nin | (iv << 16));
            aen[pos] = rec;
        }
    } else {
        int b2 = blockIdx.x - 313;
        int j = t & 31, cp = t >> 5;
        float s = 0.f, q = 0.f;
        for (int n = b2*8 + cp; n < N_; n += 64*8) {
            float w = (float)wsi[OFF_DEGIN + n];
            float p = ws[OFF_P + (size_t)n*HID + j];
            s += w*p; q += w*p*p;
        }
        shS[t] = s; shQ[t] = q;
        __syncthreads();
        if (t < 32) {
            float S = 0.f, Qq = 0.f;
            for (int c = 0; c < 8; ++c) { S += shS[t + 32*c]; Qq += shQ[t + 32*c]; }
            atomicAdd(&ws[OFF_SUMP + t], S);
            atomicAdd(&ws[OFF_SQP  + t], Qq);
        }
    }
}

// =======================================================================
// K_D: segment reduce, latency-optimized.
//   Group of 32 lanes per node. Metadata loaded coalesced 32-edges-at-a-
//   time into registers, broadcast via __shfl; only memory op in the inner
//   loop is the coalesced 128B P[nin] read, hoisted 4-wide for MLP.
// =======================================================================
__global__ __launch_bounds__(256)
void k_D(const float* __restrict__ g_msg, const float* __restrict__ beta_msg,
         float* __restrict__ ws) {
    __shared__ float A[4][32*33];   // A1_s0, A0_s0, A1_s1, A0_s1 (padded rows)
    __shared__ float Bv[4][32];     // bias rows
    __shared__ float zl[8][4][32];
    __shared__ float shS[256], shQ[256];
    __shared__ int s_slot0, s_slot1;
    int* wsi = (int*)ws;
    int t = threadIdx.x, g = t >> 5, j = t & 31;

    if (t == 0) {
        int a0 = -1, a1 = -1;
        for (int i = 0; i < NIV; ++i)
            if (wsi[OFF_OCC + i] > 0) { if (a0 < 0) a0 = i; else if (a1 < 0) a1 = i; }
        s_slot0 = a0; s_slot1 = a1;
    }
    __syncthreads();
    int s0 = s_slot0, s1 = s_slot1;

    for (int idx = t; idx < 1024; idx += 256) {
        int jj = idx >> 5, kk = idx & 31;
        A[0][jj*33+kk] = (s0 >= 0) ? ws[OFF_C1 + (size_t)s0*1056 + 32 + idx] : 0.f;
        A[1][jj*33+kk] = (s0 >= 0) ? ws[OFF_C0 + (size_t)s0*1056 + 32 + idx] : 0.f;
        A[2][jj*33+kk] = (s1 >= 0) ? ws[OFF_C1 + (size_t)s1*1056 + 32 + idx] : 0.f;
        A[3][jj*33+kk] = (s1 >= 0) ? ws[OFF_C0 + (size_t)s1*1056 + 32 + idx] : 0.f;
    }
    if (t < 32) {
        Bv[0][t] = (s0 >= 0) ? ws[OFF_C1 + (size_t)s0*1056 + t] : 0.f;
        Bv[1][t] = (s0 >= 0) ? ws[OFF_C0 + (size_t)s0*1056 + t] : 0.f;
        Bv[2][t] = (s1 >= 0) ? ws[OFF_C1 + (size_t)s1*1056 + t] : 0.f;
        Bv[3][t] = (s1 >= 0) ? ws[OFF_C0 + (size_t)s1*1056 + t] : 0.f;
    }
    // bn_msg constants for column j
    float mP = ws[OFF_SUMP + j] * (1.f/E_);
    float vP = ws[OFF_SQP  + j] * (1.f/E_) - mP*mP;
    float istd = 1.f / sqrtf(vP + EPS);
    float gc = g_msg[j]*istd, bc = beta_msg[j] - mP*gc;
    __syncthreads();

    int n = blockIdx.x*8 + g;
    int st = wsi[OFF_STARTS + n], en = wsi[OFF_STARTS + n + 1];
    float za0 = 0.f, zb0 = 0.f, za1 = 0.f, zb1 = 0.f;
    float suma0 = 0.f, suma1 = 0.f, c0f = 0.f, c1f = 0.f, rfall = 0.f;
    const float2* aen = (const float2*)(ws + OFF_AEN);

    for (int base = st; base < en; base += 32) {
        int cnt = en - base; if (cnt > 32) cnt = 32;
        float a_j = 0.f; int meta_j = 0;
        if (j < cnt) {
            float2 r = aen[base + j];
            a_j = r.x; meta_j = __float_as_int(r.y);
        }
        for (int k = 0; k < cnt; k += 4) {
            float pv[4], aa[4]; int ivv[4]; bool val[4];
            #pragma unroll
            for (int u = 0; u < 4; ++u) {
                int kk = (k + u) & 31;
                aa[u]  = __shfl(a_j, kk, 32);
                int mt = __shfl(meta_j, kk, 32);
                val[u] = (k + u) < cnt;
                int nin = mt & 0xFFFF; ivv[u] = mt >> 16;
                pv[u] = ws[OFF_P + (size_t)nin*HID + j];
            }
            #pragma unroll
            for (int u = 0; u < 4; ++u) {
                if (!val[u]) continue;   // uniform within the 32-lane group
                float q = fmaxf(fmaf(gc, pv[u], bc), 0.f);
                float a = aa[u]; int iv = ivv[u];
                if (iv == s0)      { za0 = fmaf(a, q, za0); zb0 += q; suma0 += a; c0f += 1.f; }
                else if (iv == s1) { za1 = fmaf(a, q, za1); zb1 += q; suma1 += a; c1f += 1.f; }
                else {  // general fallback (not taken with given inputs)
                    const float* C1r = ws + OFF_C1 + (size_t)iv*1056;
                    const float* C0r = ws + OFF_C0 + (size_t)iv*1056;
                    float d1 = 0.f, d0 = 0.f;
                    for (int k2 = 0; k2 < 32; ++k2) {
                        float qk = __shfl(q, k2, 32);
                        d1 += C1r[32 + j*32 + k2] * qk;
                        d0 += C0r[32 + j*32 + k2] * qk;
                    }
                    rfall += a*(d1 + C1r[j]) + (d0 + C0r[j]);
                }
            }
        }
    }
    zl[g][0][j] = za0; zl[g][1][j] = zb0; zl[g][2][j] = za1; zl[g][3][j] = zb1;
    __syncthreads();

    float acc = rfall;
    if (s0 >= 0) acc += suma0*Bv[0][j] + c0f*Bv[1][j];
    if (s1 >= 0) acc += suma1*Bv[2][j] + c1f*Bv[3][j];
    const float* z0 = zl[g][0]; const float* z1 = zl[g][1];
    const float* z2 = zl[g][2]; const float* z3 = zl[g][3];
    #pragma unroll 4
    for (int k = 0; k < 32; ++k) {
        acc += A[0][j*33+k]*z0[k] + A[1][j*33+k]*z1[k]
             + A[2][j*33+k]*z2[k] + A[3][j*33+k]*z3[k];
    }
    ws[OFF_UPD + (size_t)n*HID + j] = acc;

    // fused upd stats
    shS[t] = acc; shQ[t] = acc*acc;
    __syncthreads();
    if (t < 32) {
        float S = 0.f, Qq = 0.f;
        for (int c = 0; c < 8; ++c) { S += shS[t + 32*c]; Qq += shQ[t + 32*c]; }
        atomicAdd(&ws[OFF_SUMU + t], S);
        atomicAdd(&ws[OFF_SQU  + t], Qq);
    }
}

// =======================================================================
// K_F: out_pre = relu(bn(upd)) @ w2.T + b2 ; accumulate out stats
// =======================================================================
__global__ __launch_bounds__(256)
void k_F(const float* __restrict__ w2, const float* __restrict__ b2,
         const float* __restrict__ g_upd, const float* __restrict__ beta_upd,
         float* __restrict__ ws, float* __restrict__ out) {
    __shared__ float U[2][HID];
    __shared__ float shS[256], shQ[256];
    int t = threadIdx.x, nh = t >> 7, o = t & 127;
    float gc = 0.f, bc = 0.f;
    if (o < 32) {
        float m = ws[OFF_SUMU + o]*(1.f/N_);
        float v = ws[OFF_SQU  + o]*(1.f/N_) - m*m;
        float istd = 1.f/sqrtf(v + EPS);
        gc = g_upd[o]*istd; bc = beta_upd[o] - m*gc;
    }
    float w2r[32];
    for (int k = 0; k < 32; ++k) w2r[k] = w2[o*32 + k];
    float bo = b2[o];
    float sO = 0.f, qO = 0.f;
    for (int base = blockIdx.x*2; base < N_; base += gridDim.x*2) {
        int n = base + nh;
        if (o < 32) {
            float u = ws[OFF_UPD + (size_t)n*HID + o];
            U[nh][o] = fmaxf(fmaf(gc, u, bc), 0.f);
        }
        __syncthreads();
        float v = bo;
        for (int k = 0; k < 32; ++k) v = fmaf(w2r[k], U[nh][k], v);
        out[(size_t)n*OUTD + o] = v;
        sO += v; qO += v*v;
        __syncthreads();
    }
    shS[t] = sO; shQ[t] = qO;
    __syncthreads();
    if (t < 128) {
        atomicAdd(&ws[OFF_SUMO + t], shS[t] + shS[t+128]);
        atomicAdd(&ws[OFF_SQO  + t], shQ[t] + shQ[t+128]);
    }
}

// =======================================================================
// K_G: final output batch-norm (in-place)
// =======================================================================
__global__ __launch_bounds__(256)
void k_G(const float* __restrict__ g_out, const float* __restrict__ beta_out,
         const float* __restrict__ ws, float* __restrict__ out) {
    int g = blockIdx.x*blockDim.x + threadIdx.x;
    if (g >= N_*OUTD) return;
    int o = g & 127;
    float m = ws[OFF_SUMO + o]*(1.f/N_);
    float v = ws[OFF_SQO  + o]*(1.f/N_) - m*m;
    float istd = 1.f/sqrtf(v + EPS);
    out[g] = g_out[o]*istd*(out[g] - m) + beta_out[o];
}

// ---------------- launch -----------------------------------------------------
extern "C" void kernel_launch(void* const* d_in, const int* in_sizes, int n_in,
                              void* d_out, int out_size, void* d_ws, size_t ws_size,
                              hipStream_t stream) {
    const float* H        = (const float*)d_in[0];
    const float* ea       = (const float*)d_in[1];
    const int*   edges    = (const int*)  d_in[2];
    const float* w1       = (const float*)d_in[3];
    const float* b1       = (const float*)d_in[4];
    const float* kw1      = (const float*)d_in[5];
    const float* kb1      = (const float*)d_in[6];
    const float* kw2      = (const float*)d_in[7];
    const float* kb2      = (const float*)d_in[8];
    const float* w2       = (const float*)d_in[9];
    const float* b2       = (const float*)d_in[10];
    const float* g_in     = (const float*)d_in[11];
    const float* beta_in  = (const float*)d_in[12];
    const float* g_msg    = (const float*)d_in[13];
    const float* beta_msg = (const float*)d_in[14];
    const float* g_upd    = (const float*)d_in[15];
    const float* beta_upd = (const float*)d_in[16];
    const float* g_out    = (const float*)d_in[17];
    const float* beta_out = (const float*)d_in[18];
    float* ws  = (float*)d_ws;
    float* out = (float*)d_out;

    hipMemsetAsync(d_ws, 0, ZERO_CNT*sizeof(float), stream);
    hipLaunchKernelGGL(k_A, dim3(474),  dim3(256), 0, stream, H, ea, edges, kw1, kb1, kw2, kb2, ws);
    hipLaunchKernelGGL(k_B, dim3(1251), dim3(256), 0, stream, H, w1, b1, g_in, beta_in, ws);
    hipLaunchKernelGGL(k_C, dim3(377),  dim3(256), 0, stream, ea, edges, kw1, kb1, ws);
    hipLaunchKernelGGL(k_D, dim3(1250), dim3(256), 0, stream, g_msg, beta_msg, ws);
    hipLaunchKernelGGL(k_F, dim3(250),  dim3(256), 0, stream, w2, b2, g_upd, beta_upd, ws, out);
    hipLaunchKernelGGL(k_G, dim3((N_*OUTD + 255)/256), dim3(256), 0, stream, g_out, beta_out, ws, out);
}